// Round 7
// baseline (106.525 us; speedup 1.0000x reference)
//
#include <hip/hip_runtime.h>

// ProteinMapper round 7: occupancy was the bottleneck (VALUBusy 13%, HBM 22%,
// conflicts 0, occupancy 19% => latency-bound at 2 waves/SIMD, structural for
// 1 thread/residue). Now 4 threads per residue: each redundantly builds the 8
// frames in registers, then handles 3-4 atoms. 524288 threads -> ~5 waves/SIMD.
// s_out staging dropped (round-6 proved write path neutral; L2 merges).

constexpr int NRES_TOTAL = 64 * 2048;     // 131072 residues
constexpr int NRT = 21;                   // restypes
constexpr int NG  = 8;                    // groups
constexpr int NA  = 14;                   // atoms
constexpr int BLK = 256;
constexpr int RPB = BLK / 4;              // 64 residues per block

__global__ __launch_bounds__(256) void protein_mapper_kernel(
    const float* __restrict__ bb_rots,        // (B,L,3,3)
    const float* __restrict__ bb_trans,       // (B,L,3)
    const float* __restrict__ angles,         // (B,L,7,2)
    const int*   __restrict__ aatype,         // (B,L)
    const float* __restrict__ default_frames, // (21,8,4,4)
    const int*   __restrict__ group_idx,      // (21,14)
    const float* __restrict__ atom_mask,      // (21,14)
    const float* __restrict__ lit_positions,  // (21,14,3)
    float* __restrict__ out)                  // (B,L,14,3)
{
    // ---- LDS: transposed tables [element][aa] (bank-conflict-free) ----
    __shared__ float s_frames[128 * NRT];     // 10752 B
    __shared__ int   s_gidx[NA * NRT];        //  1176 B
    __shared__ float s_mask[NA * NRT];        //  1176 B
    __shared__ float s_lit[NA * 3 * NRT];     //  3528 B

    const int t   = threadIdx.x;
    const int res = blockIdx.x * RPB + (t >> 2);   // grid exact: no OOB
    const int sub = t & 3;                          // atom quarter

    // ---- issue per-residue input loads FIRST (latency hides under staging) ----
    const int aa_early = aatype[res];
    float2 ang[7];
    {
        const float2* angp = reinterpret_cast<const float2*>(angles + (size_t)res * 14);
        #pragma unroll
        for (int g = 0; g < 7; ++g) ang[g] = angp[g];
    }
    const float* br = bb_rots + (size_t)res * 9;
    const float b00 = br[0], b01 = br[1], b02 = br[2];
    const float b10 = br[3], b11 = br[4], b12 = br[5];
    const float b20 = br[6], b21 = br[7], b22 = br[8];
    const float* btp = bb_trans + (size_t)res * 3;
    const float bt0 = btp[0], bt1 = btp[1], bt2 = btp[2];

    // ---- stage tables (transposed) ----
    for (int n = t; n < NRT * 128; n += BLK) {
        const int aa = n / 128, j = n % 128;
        s_frames[j * NRT + aa] = default_frames[n];
    }
    for (int n = t; n < NRT * NA; n += BLK) {
        const int aa = n / NA, a = n % NA;
        s_gidx[a * NRT + aa] = group_idx[n];
        s_mask[a * NRT + aa] = atom_mask[n];
    }
    for (int n = t; n < NRT * NA * 3; n += BLK) {
        const int aa = n / (NA * 3), k = n % (NA * 3);
        s_lit[k * NRT + aa] = lit_positions[n];
    }
    __syncthreads();

    const int aa = aa_early;

    // ---- sin/cos per group (group 0 = identity) ----
    float sv[NG], cv[NG];
    sv[0] = 0.0f; cv[0] = 1.0f;
    #pragma unroll
    for (int g = 1; g < NG; ++g) { sv[g] = ang[g - 1].x; cv[g] = ang[g - 1].y; }

    // ---- build local frames: G[g][0..8] = dR @ rotx(s,c), G[g][9..11] = dt ----
    float G[NG][12];
    #pragma unroll
    for (int g = 0; g < NG; ++g) {
        const float cg = cv[g], sg = sv[g];
        #pragma unroll
        for (int r = 0; r < 3; ++r) {
            const float a0 = s_frames[(g * 16 + r * 4 + 0) * NRT + aa];
            const float a1 = s_frames[(g * 16 + r * 4 + 1) * NRT + aa];
            const float a2 = s_frames[(g * 16 + r * 4 + 2) * NRT + aa];
            const float a3 = s_frames[(g * 16 + r * 4 + 3) * NRT + aa];
            G[g][r * 3 + 0] = a0;
            G[g][r * 3 + 1] = cg * a1 + sg * a2;
            G[g][r * 3 + 2] = cg * a2 - sg * a1;
            G[g][9 + r]     = a3;
        }
    }

    // ---- compose chain for groups 5,6,7 ----
    #pragma unroll
    for (int g = 5; g < NG; ++g) {
        float Q[12];
        #pragma unroll
        for (int r = 0; r < 3; ++r) {
            const float p0 = G[g - 1][r * 3 + 0];
            const float p1 = G[g - 1][r * 3 + 1];
            const float p2 = G[g - 1][r * 3 + 2];
            #pragma unroll
            for (int cdx = 0; cdx < 3; ++cdx)
                Q[r * 3 + cdx] = p0 * G[g][cdx] + p1 * G[g][3 + cdx] + p2 * G[g][6 + cdx];
            Q[9 + r] = p0 * G[g][9] + p1 * G[g][10] + p2 * G[g][11] + G[g - 1][9 + r];
        }
        #pragma unroll
        for (int k = 0; k < 12; ++k) G[g][k] = Q[k];
    }

    // ---- this thread's 4 atoms: a = 4*sub + j (a<14) ----
    float q[12];
    #pragma unroll
    for (int j = 0; j < 4; ++j) {
        const int a = 4 * sub + j;
        if (a < NA) {
            const int   ga = s_gidx[a * NRT + aa];
            const float m_ = s_mask[a * NRT + aa];
            const float lx = s_lit[(a * 3 + 0) * NRT + aa];
            const float ly = s_lit[(a * 3 + 1) * NRT + aa];
            const float lz = s_lit[(a * 3 + 2) * NRT + aa];
            const bool b0_ = ga & 1, b1_ = ga & 2, b2_ = ga & 4;
            float S[12];
            #pragma unroll
            for (int e = 0; e < 12; ++e) {
                const float t0 = b0_ ? G[1][e] : G[0][e];
                const float t1 = b0_ ? G[3][e] : G[2][e];
                const float t2 = b0_ ? G[5][e] : G[4][e];
                const float t3 = b0_ ? G[7][e] : G[6][e];
                const float u0 = b1_ ? t1 : t0;
                const float u1 = b1_ ? t3 : t2;
                S[e] = b2_ ? u1 : u0;
            }
            const float px = S[0] * lx + S[1] * ly + S[2] * lz + S[9];
            const float py = S[3] * lx + S[4] * ly + S[5] * lz + S[10];
            const float pz = S[6] * lx + S[7] * ly + S[8] * lz + S[11];
            q[j * 3 + 0] = (b00 * px + b01 * py + b02 * pz + bt0) * m_;
            q[j * 3 + 1] = (b10 * px + b11 * py + b12 * pz + bt1) * m_;
            q[j * 3 + 2] = (b20 * px + b21 * py + b22 * pz + bt2) * m_;
        }
    }

    // ---- store: thread covers float2 slots [6*sub, 6*sub+6) of this residue
    //      (sub 3: only 3 slots). Wave covers 16 residues' full 168B rows. ----
    float2* o2 = reinterpret_cast<float2*>(out) + (size_t)res * 21 + sub * 6;
    const int nf2 = (sub == 3) ? 3 : 6;
    #pragma unroll
    for (int k = 0; k < 6; ++k) {
        if (k < nf2) {
            float2 v; v.x = q[2 * k + 0]; v.y = q[2 * k + 1];
            o2[k] = v;
        }
    }
}

extern "C" void kernel_launch(void* const* d_in, const int* in_sizes, int n_in,
                              void* d_out, int out_size, void* d_ws, size_t ws_size,
                              hipStream_t stream) {
    const float* bb_rots        = (const float*)d_in[0];
    const float* bb_trans       = (const float*)d_in[1];
    const float* angles         = (const float*)d_in[2];
    const int*   aatype         = (const int*)d_in[3];
    const float* default_frames = (const float*)d_in[4];
    const int*   group_idx      = (const int*)d_in[5];
    const float* atom_mask      = (const float*)d_in[6];
    const float* lit_positions  = (const float*)d_in[7];
    float* out = (float*)d_out;

    const int blocks = NRES_TOTAL / RPB;   // 2048, exact
    protein_mapper_kernel<<<blocks, BLK, 0, stream>>>(
        bb_rots, bb_trans, angles, aatype,
        default_frames, group_idx, atom_mask, lit_positions, out);
}

// Round 8
// 96.674 us; speedup vs baseline: 1.1019x; 1.1019x over previous
//
#include <hip/hip_runtime.h>

// ProteinMapper round 8: r5 structure (best measured: 93.5) with ONE change:
// __launch_bounds__(256, 2). Theory: r5's VGPR_Count=96 < the 96-float live
// G[8][12] array => compiler spilled G to scratch (L2-latency round-trips),
// explaining 45us dispatch with all pipes idle (VALU 13%, HBM 22%, LDS 0).
// (256,2) raises the per-wave VGPR cap to 256 (occupancy is grid-limited to
// 2 waves/SIMD regardless, so no occupancy cost).

constexpr int NRES_TOTAL = 64 * 2048;     // 131072 residues
constexpr int NRT = 21;                   // restypes
constexpr int NG  = 8;                    // groups
constexpr int NA  = 14;                   // atoms

__global__ __launch_bounds__(256, 2) void protein_mapper_kernel(
    const float* __restrict__ bb_rots,        // (B,L,3,3)
    const float* __restrict__ bb_trans,       // (B,L,3)
    const float* __restrict__ angles,         // (B,L,7,2)
    const int*   __restrict__ aatype,         // (B,L)
    const float* __restrict__ default_frames, // (21,8,4,4)
    const int*   __restrict__ group_idx,      // (21,14)
    const float* __restrict__ atom_mask,      // (21,14)
    const float* __restrict__ lit_positions,  // (21,14,3)
    float* __restrict__ out)                  // (B,L,14,3)
{
    // ---- stage small tables into LDS, TRANSPOSED to [element][aa] ----
    __shared__ float s_frames[128 * NRT];     // [g*16+r*4+c][aa]
    __shared__ int   s_gidx[NA * NRT];        // [a][aa]
    __shared__ float s_mask[NA * NRT];        // [a][aa]
    __shared__ float s_lit[NA * 3 * NRT];     // [a*3+c][aa]

    for (int n = threadIdx.x; n < NRT * 128; n += 256) {
        const int aa = n / 128, j = n % 128;
        s_frames[j * NRT + aa] = default_frames[n];
    }
    for (int n = threadIdx.x; n < NRT * NA; n += 256) {
        const int aa = n / NA, a = n % NA;
        s_gidx[a * NRT + aa] = group_idx[n];
        s_mask[a * NRT + aa] = atom_mask[n];
    }
    for (int n = threadIdx.x; n < NRT * NA * 3; n += 256) {
        const int aa = n / (NA * 3), k = n % (NA * 3);
        s_lit[k * NRT + aa] = lit_positions[n];
    }
    __syncthreads();

    const int i = blockIdx.x * 256 + threadIdx.x;   // grid exact: no OOB guard
    const int aa = aatype[i];

    // ---- sin/cos per group (group 0 = backbone identity [s=0,c=1]) ----
    float sv[NG], cv[NG];
    sv[0] = 0.0f; cv[0] = 1.0f;
    const float2* angp = reinterpret_cast<const float2*>(angles + (size_t)i * 14);
    #pragma unroll
    for (int g = 1; g < NG; ++g) {
        float2 sc = angp[g - 1];
        sv[g] = sc.x;   // sin slot
        cv[g] = sc.y;   // cos slot
    }

    // ---- build local frames: G[g][0..8] = dR @ rotx(s,c), G[g][9..11] = dt ----
    // rotx: col0 = dRcol0 ; col1 = c*dRcol1 + s*dRcol2 ; col2 = c*dRcol2 - s*dRcol1
    float G[NG][12];
    #pragma unroll
    for (int g = 0; g < NG; ++g) {
        const float cg = cv[g], sg = sv[g];
        #pragma unroll
        for (int r = 0; r < 3; ++r) {
            const float a0 = s_frames[(g * 16 + r * 4 + 0) * NRT + aa];
            const float a1 = s_frames[(g * 16 + r * 4 + 1) * NRT + aa];
            const float a2 = s_frames[(g * 16 + r * 4 + 2) * NRT + aa];
            const float a3 = s_frames[(g * 16 + r * 4 + 3) * NRT + aa];
            G[g][r * 3 + 0] = a0;
            G[g][r * 3 + 1] = cg * a1 + sg * a2;
            G[g][r * 3 + 2] = cg * a2 - sg * a1;
            G[g][9 + r]     = a3;
        }
    }

    // ---- compose chain for groups 5,6,7: G[g] <- G[g-1] ∘ G[g] ----
    #pragma unroll
    for (int g = 5; g < NG; ++g) {
        float Q[12];
        #pragma unroll
        for (int r = 0; r < 3; ++r) {
            const float p0 = G[g - 1][r * 3 + 0];
            const float p1 = G[g - 1][r * 3 + 1];
            const float p2 = G[g - 1][r * 3 + 2];
            #pragma unroll
            for (int cdx = 0; cdx < 3; ++cdx)
                Q[r * 3 + cdx] = p0 * G[g][cdx] + p1 * G[g][3 + cdx] + p2 * G[g][6 + cdx];
            Q[9 + r] = p0 * G[g][9] + p1 * G[g][10] + p2 * G[g][11] + G[g - 1][9 + r];
        }
        #pragma unroll
        for (int k = 0; k < 12; ++k) G[g][k] = Q[k];
    }

    // ---- backbone frame (applied per-atom: bbR @ (Rsel@lit + tsel) + bbt) ----
    const float* br = bb_rots + (size_t)i * 9;
    const float b00 = br[0], b01 = br[1], b02 = br[2];
    const float b10 = br[3], b11 = br[4], b12 = br[5];
    const float b20 = br[6], b21 = br[7], b22 = br[8];
    const float* btp = bb_trans + (size_t)i * 3;
    const float bt0 = btp[0], bt1 = btp[1], bt2 = btp[2];

    // per-atom: 3-level cndmask tree selects G[ga] (static element indexing)
    auto atom_pos = [&](int a, float& qx, float& qy, float& qz) {
        const int   ga = s_gidx[a * NRT + aa];
        const float m_ = s_mask[a * NRT + aa];
        const float lx = s_lit[(a * 3 + 0) * NRT + aa];
        const float ly = s_lit[(a * 3 + 1) * NRT + aa];
        const float lz = s_lit[(a * 3 + 2) * NRT + aa];
        const bool b0_ = ga & 1, b1_ = ga & 2, b2_ = ga & 4;
        float S[12];
        #pragma unroll
        for (int e = 0; e < 12; ++e) {
            const float t0 = b0_ ? G[1][e] : G[0][e];
            const float t1 = b0_ ? G[3][e] : G[2][e];
            const float t2 = b0_ ? G[5][e] : G[4][e];
            const float t3 = b0_ ? G[7][e] : G[6][e];
            const float u0 = b1_ ? t1 : t0;
            const float u1 = b1_ ? t3 : t2;
            S[e] = b2_ ? u1 : u0;
        }
        const float px = S[0] * lx + S[1] * ly + S[2] * lz + S[9];
        const float py = S[3] * lx + S[4] * ly + S[5] * lz + S[10];
        const float pz = S[6] * lx + S[7] * ly + S[8] * lz + S[11];
        qx = (b00 * px + b01 * py + b02 * pz + bt0) * m_;
        qy = (b10 * px + b11 * py + b12 * pz + bt1) * m_;
        qz = (b20 * px + b21 * py + b22 * pz + bt2) * m_;
    };

    // ---- atoms in pairs -> 3 float2 stores per pair (offset 168 B, 8B-aligned) ----
    float2* op2 = reinterpret_cast<float2*>(out + (size_t)i * (NA * 3));
    #pragma unroll
    for (int ap = 0; ap < NA / 2; ++ap) {
        float qx0, qy0, qz0, qx1, qy1, qz1;
        atom_pos(2 * ap + 0, qx0, qy0, qz0);
        atom_pos(2 * ap + 1, qx1, qy1, qz1);
        float2 v0; v0.x = qx0; v0.y = qy0;
        float2 v1; v1.x = qz0; v1.y = qx1;
        float2 v2; v2.x = qy1; v2.y = qz1;
        op2[3 * ap + 0] = v0;
        op2[3 * ap + 1] = v1;
        op2[3 * ap + 2] = v2;
    }
}

extern "C" void kernel_launch(void* const* d_in, const int* in_sizes, int n_in,
                              void* d_out, int out_size, void* d_ws, size_t ws_size,
                              hipStream_t stream) {
    const float* bb_rots        = (const float*)d_in[0];
    const float* bb_trans       = (const float*)d_in[1];
    const float* angles         = (const float*)d_in[2];
    const int*   aatype         = (const int*)d_in[3];
    const float* default_frames = (const float*)d_in[4];
    const int*   group_idx      = (const int*)d_in[5];
    const float* atom_mask      = (const float*)d_in[6];
    const float* lit_positions  = (const float*)d_in[7];
    float* out = (float*)d_out;

    const int blocks = NRES_TOTAL / 256;   // 512, exact
    protein_mapper_kernel<<<blocks, 256, 0, stream>>>(
        bb_rots, bb_trans, angles, aatype,
        default_frames, group_idx, atom_mask, lit_positions, out);
}